// Round 1
// baseline (2083.608 us; speedup 1.0000x reference)
//
#include <hip/hip_runtime.h>
#include <math.h>

// Problem constants
constexpr int WVOC = 50000;
constexpr int CVOC = 100;
constexpr int NCLS = 18;
constexpr int EE   = 512;   // word emb
constexpr int HHm  = 512;   // main GRU hidden
constexpr int CEc  = 128;   // char emb
constexpr int CHc  = 256;   // char GRU hidden
constexpr int BB   = 64;
constexpr int TT   = 64;
constexpr int CCh  = 16;    // chars per word
constexpr int NTOK = BB*TT;       // 4096
constexpr int G3C  = 3*CHc;       // 768
constexpr int G3H  = 3*HHm;       // 1536
constexpr int KIN  = EE + CHc;    // 768

__device__ __forceinline__ float sigmoidf_(float x){ return 1.0f/(1.0f + __expf(-x)); }
__device__ __forceinline__ float tanhf_(float x){ return 1.0f - 2.0f/(__expf(2.0f*x) + 1.0f); }

// ---------------------------------------------------------------------------
// K1: char input-projection table U2[c][g] = char_emb_W[c] . char_Wih[g] + bih[g]
//     (+ bhh[g] folded for r,z gates only, g < 512)
__global__ void k_uchar(const float* __restrict__ cemb, const float* __restrict__ wih,
                        const float* __restrict__ bih, const float* __restrict__ bhh,
                        float* __restrict__ U2){
  const int c = blockIdx.x;        // 0..99
  const int g = threadIdx.x;       // 0..767
  const float* a = cemb + (size_t)c*CEc;
  const float* w = wih  + (size_t)g*CEc;
  float s = 0.f;
  for(int k=0;k<CEc;k++) s = fmaf(a[k], w[k], s);
  s += bih[g];
  if(g < 2*CHc) s += bhh[g];
  U2[(size_t)c*G3C + g] = s;
}

// ---------------------------------------------------------------------------
// generic transpose: in[R][C] -> out[C][R]
__global__ void k_transpose(const float* __restrict__ in, float* __restrict__ out,
                            int R, int C){
  int idx = blockIdx.x*blockDim.x + threadIdx.x;
  if(idx >= R*C) return;
  int k = idx / R;     // out row (0..C-1)
  int j = idx % R;     // out col (0..R-1)
  out[idx] = in[(size_t)j*C + k];
}

// ---------------------------------------------------------------------------
// K2: char GRU. 8 words per 256-thread block, h in LDS, 16 steps locally.
// thread = h-column (0..255); gh via WhhT (transposed, coalesced rows).
__global__ __launch_bounds__(256) void k_chargru(
    const int* __restrict__ chars, const float* __restrict__ U2,
    const float* __restrict__ WhhT, const float* __restrict__ bhh,
    float* __restrict__ char_h){
  __shared__ float hsh[8][CHc];     // 8KB
  __shared__ int chsh[8];
  const int tid = threadIdx.x;
  const int w0 = blockIdx.x * 8;
  const float bhn = bhh[2*CHc + tid];
  #pragma unroll
  for(int w=0; w<8; w++) hsh[w][tid] = 0.f;
  __syncthreads();
  for(int t=0; t<CCh; t++){
    if(tid < 8) chsh[tid] = chars[(size_t)(w0 + tid)*CCh + t];
    __syncthreads();
    float ar[8], az[8], an[8];
    #pragma unroll
    for(int w=0;w<8;w++){ ar[w]=0.f; az[w]=0.f; an[w]=0.f; }
    for(int k=0; k<CHc; k+=4){
      float wr[4], wz[4], wn[4];
      #pragma unroll
      for(int i=0;i<4;i++){
        const float* row = WhhT + (size_t)(k+i)*G3C;
        wr[i]=row[tid]; wz[i]=row[CHc+tid]; wn[i]=row[2*CHc+tid];
      }
      #pragma unroll
      for(int w=0;w<8;w++){
        float4 hv = *reinterpret_cast<const float4*>(&hsh[w][k]);
        ar[w] = fmaf(hv.x,wr[0], fmaf(hv.y,wr[1], fmaf(hv.z,wr[2], fmaf(hv.w,wr[3], ar[w]))));
        az[w] = fmaf(hv.x,wz[0], fmaf(hv.y,wz[1], fmaf(hv.z,wz[2], fmaf(hv.w,wz[3], az[w]))));
        an[w] = fmaf(hv.x,wn[0], fmaf(hv.y,wn[1], fmaf(hv.z,wn[2], fmaf(hv.w,wn[3], an[w]))));
      }
    }
    __syncthreads();
    #pragma unroll
    for(int w=0;w<8;w++){
      const float* u = U2 + (size_t)chsh[w]*G3C;
      float r = sigmoidf_(u[tid]        + ar[w]);
      float z = sigmoidf_(u[CHc+tid]    + az[w]);
      float n = tanhf_   (u[2*CHc+tid]  + r*(an[w] + bhn));
      float hp = hsh[w][tid];
      hsh[w][tid] = (1.f - z)*n + z*hp;
    }
    __syncthreads();
  }
  #pragma unroll
  for(int w=0;w<8;w++) char_h[(size_t)(w0+w)*CHc + tid] = hsh[w][tid];
}

// ---------------------------------------------------------------------------
// K3: gx_main[token][g] = concat(word_emb_W[x[token]], char_h[token]) . gru_Wih[g]
//     + gbih[g] (+ gbhh[g] for g < 1024).  GEMM M=4096, N=1536, K=768, 64x64 tiles.
__global__ __launch_bounds__(256) void k_gxmain(
    const int* __restrict__ x, const float* __restrict__ wemb,
    const float* __restrict__ char_h, const float* __restrict__ WihT,
    const float* __restrict__ bih, const float* __restrict__ bhh,
    float* __restrict__ gx){
  __shared__ float As[64][17];
  __shared__ float Bs[16][64];
  const int tid = threadIdx.x;
  const int rb = blockIdx.x * 64;
  const int nb = blockIdx.y * 64;
  const int tr = tid >> 4, tc = tid & 15;
  const int arr = tid >> 2, ak0 = (tid & 3)*4;
  const int bk = tid >> 4, bj0 = (tid & 15)*4;
  const int arow = rb + arr;
  const int wid = x[arow];
  const float* wrow = wemb + (size_t)wid*EE;
  const float* crow = char_h + (size_t)arow*CHc;
  float acc[4][4];
  #pragma unroll
  for(int i=0;i<4;i++)
    #pragma unroll
    for(int j=0;j<4;j++) acc[i][j]=0.f;
  for(int kb=0; kb<KIN; kb+=16){
    int kg = kb + ak0;
    const float4* src = (kg < EE) ? reinterpret_cast<const float4*>(&wrow[kg])
                                  : reinterpret_cast<const float4*>(&crow[kg-EE]);
    float4 av = *src;
    As[arr][ak0+0]=av.x; As[arr][ak0+1]=av.y; As[arr][ak0+2]=av.z; As[arr][ak0+3]=av.w;
    *reinterpret_cast<float4*>(&Bs[bk][bj0]) =
        *reinterpret_cast<const float4*>(&WihT[(size_t)(kb+bk)*G3H + nb + bj0]);
    __syncthreads();
    #pragma unroll
    for(int k=0;k<16;k++){
      float a0=As[tr*4+0][k], a1=As[tr*4+1][k], a2=As[tr*4+2][k], a3=As[tr*4+3][k];
      float b0=Bs[k][tc*4+0], b1=Bs[k][tc*4+1], b2=Bs[k][tc*4+2], b3=Bs[k][tc*4+3];
      acc[0][0]=fmaf(a0,b0,acc[0][0]); acc[0][1]=fmaf(a0,b1,acc[0][1]);
      acc[0][2]=fmaf(a0,b2,acc[0][2]); acc[0][3]=fmaf(a0,b3,acc[0][3]);
      acc[1][0]=fmaf(a1,b0,acc[1][0]); acc[1][1]=fmaf(a1,b1,acc[1][1]);
      acc[1][2]=fmaf(a1,b2,acc[1][2]); acc[1][3]=fmaf(a1,b3,acc[1][3]);
      acc[2][0]=fmaf(a2,b0,acc[2][0]); acc[2][1]=fmaf(a2,b1,acc[2][1]);
      acc[2][2]=fmaf(a2,b2,acc[2][2]); acc[2][3]=fmaf(a2,b3,acc[2][3]);
      acc[3][0]=fmaf(a3,b0,acc[3][0]); acc[3][1]=fmaf(a3,b1,acc[3][1]);
      acc[3][2]=fmaf(a3,b2,acc[3][2]); acc[3][3]=fmaf(a3,b3,acc[3][3]);
    }
    __syncthreads();
  }
  #pragma unroll
  for(int i=0;i<4;i++){
    int row = rb + tr*4 + i;
    #pragma unroll
    for(int j=0;j<4;j++){
      int g = nb + tc*4 + j;
      float v = acc[i][j] + bih[g] + (g < 2*HHm ? bhh[g] : 0.f);
      gx[(size_t)row*G3H + g] = v;
    }
  }
}

// ---------------------------------------------------------------------------
// K4: one main-GRU step. 128 blocks x 4 h-cols; h stored transposed hT[k][r].
__global__ __launch_bounds__(256) void k_grustep(
    const float* __restrict__ hT_in, float* __restrict__ hT_out,
    const float* __restrict__ Whh, const float* __restrict__ gx,
    const float* __restrict__ bhh, float* __restrict__ outhT, int t){
  __shared__ float wl[12][HHm];     // 24KB: 12 Whh rows (4 cols x 3 gates)
  __shared__ float hch[128][68];    // 34.8KB: h chunk [k][r] padded
  const int tid = threadIdx.x;
  const int r = tid & 63;
  const int c = tid >> 6;           // 0..3 (wave-uniform)
  const int j0 = blockIdx.x * 4;
  for(int f = tid*4; f < 12*HHm; f += 1024){
    int l = f >> 9, k = f & 511;
    int g = l >> 2, cc = l & 3;
    *reinterpret_cast<float4*>(&wl[l][k]) =
        *reinterpret_cast<const float4*>(&Whh[(size_t)(g*HHm + j0 + cc)*HHm + k]);
  }
  float accr=0.f, accz=0.f, accn=0.f;
  const float* wr = wl[c];
  const float* wz = wl[4+c];
  const float* wn = wl[8+c];
  for(int kc=0; kc<4; kc++){
    __syncthreads();
    #pragma unroll
    for(int i=0;i<8;i++){
      int f4 = i*256 + tid;
      int kk = f4 >> 4, rr = (f4 & 15)*4;
      *reinterpret_cast<float4*>(&hch[kk][rr]) =
          *reinterpret_cast<const float4*>(&hT_in[(size_t)(kc*128 + kk)*64 + rr]);
    }
    __syncthreads();
    for(int kk=0; kk<128; kk+=4){
      int kg = kc*128 + kk;
      float4 wrv = *reinterpret_cast<const float4*>(&wr[kg]);
      float4 wzv = *reinterpret_cast<const float4*>(&wz[kg]);
      float4 wnv = *reinterpret_cast<const float4*>(&wn[kg]);
      float h0 = hch[kk+0][r], h1 = hch[kk+1][r], h2 = hch[kk+2][r], h3 = hch[kk+3][r];
      accr = fmaf(h0,wrv.x, fmaf(h1,wrv.y, fmaf(h2,wrv.z, fmaf(h3,wrv.w, accr))));
      accz = fmaf(h0,wzv.x, fmaf(h1,wzv.y, fmaf(h2,wzv.z, fmaf(h3,wzv.w, accz))));
      accn = fmaf(h0,wnv.x, fmaf(h1,wnv.y, fmaf(h2,wnv.z, fmaf(h3,wnv.w, accn))));
    }
  }
  const int j = j0 + c;
  const size_t tok = (size_t)r*TT + t;
  float gxr = gx[tok*G3H + j];
  float gxz = gx[tok*G3H + HHm + j];
  float gxn = gx[tok*G3H + 2*HHm + j];
  float rg = sigmoidf_(gxr + accr);
  float zg = sigmoidf_(gxz + accz);
  float ng = tanhf_   (gxn + rg*(accn + bhh[2*HHm + j]));
  float hold = hT_in[(size_t)j*64 + r];
  float hnew = (1.f - zg)*ng + zg*hold;
  hT_out[(size_t)j*64 + r] = hnew;
  outhT[((size_t)t*HHm + j)*64 + r] = hnew;
}

// ---------------------------------------------------------------------------
// K5: classifier. One block per time-step t; logits[b,t,c] = h . cls_W[c] + cls_b[c].
__global__ __launch_bounds__(256) void k_cls(
    const float* __restrict__ outhT, const float* __restrict__ clsW,
    const float* __restrict__ clsb, float* __restrict__ out){
  __shared__ float wls[20*HHm];     // 40KB (padded 18->20 rows)
  __shared__ float hch[64][68];     // 17.4KB
  const int tid = threadIdx.x;
  const int t = blockIdx.x;
  const int r = tid & 63;
  const int q = tid >> 6;
  const int c0 = q*5;
  for(int f = tid*4; f < 20*HHm; f += 1024){
    float4 v = make_float4(0.f,0.f,0.f,0.f);
    if(f < NCLS*HHm) v = *reinterpret_cast<const float4*>(&clsW[f]);
    *reinterpret_cast<float4*>(&wls[f]) = v;
  }
  float acc[5] = {0.f,0.f,0.f,0.f,0.f};
  for(int kc=0; kc<8; kc++){
    __syncthreads();
    #pragma unroll
    for(int i=0;i<4;i++){
      int f4 = i*256 + tid;
      int kk = f4 >> 4, rr = (f4 & 15)*4;
      *reinterpret_cast<float4*>(&hch[kk][rr]) =
          *reinterpret_cast<const float4*>(&outhT[((size_t)t*HHm + kc*64 + kk)*64 + rr]);
    }
    __syncthreads();
    for(int k=0;k<64;k++){
      float hv = hch[k][r];
      #pragma unroll
      for(int i=0;i<5;i++)
        acc[i] = fmaf(hv, wls[(size_t)(c0+i)*HHm + kc*64 + k], acc[i]);
    }
  }
  #pragma unroll
  for(int i=0;i<5;i++){
    int cls = c0 + i;
    if(cls < NCLS) out[((size_t)r*TT + t)*NCLS + cls] = acc[i] + clsb[cls];
  }
}

// ---------------------------------------------------------------------------
extern "C" void kernel_launch(void* const* d_in, const int* in_sizes, int n_in,
                              void* d_out, int out_size, void* d_ws, size_t ws_size,
                              hipStream_t stream){
  const int*   x     = (const int*)d_in[0];
  const int*   chars = (const int*)d_in[1];
  const float* wemb  = (const float*)d_in[2];
  const float* cemb  = (const float*)d_in[3];
  const float* cWih  = (const float*)d_in[4];
  const float* cWhh  = (const float*)d_in[5];
  const float* cbih  = (const float*)d_in[6];
  const float* cbhh  = (const float*)d_in[7];
  const float* gWih  = (const float*)d_in[8];
  const float* gWhh  = (const float*)d_in[9];
  const float* gbih  = (const float*)d_in[10];
  const float* gbhh  = (const float*)d_in[11];
  const float* clsW  = (const float*)d_in[12];
  const float* clsb  = (const float*)d_in[13];
  float* out = (float*)d_out;
  float* ws  = (float*)d_ws;

  // workspace layout (floats)
  float* U2    = ws;                  // 100*768      = 76800
  float* WhhTc = U2 + 76800;          // 256*768      = 196608
  float* WihTm = WhhTc + 196608;      // 768*1536     = 1179648
  float* chh   = WihTm + 1179648;     // 4096*256     = 1048576
  float* gxm   = chh + 1048576;       // 4096*1536    = 6291456
  float* hA    = gxm + 6291456;       // 512*64       = 32768
  float* hB    = hA + 32768;          // 512*64       = 32768
  float* ohT   = hB + 32768;          // 64*512*64    = 2097152

  hipMemsetAsync(hA, 0, 32768*sizeof(float), stream);  // h0 = 0
  k_uchar<<<CVOC, G3C, 0, stream>>>(cemb, cWih, cbih, cbhh, U2);
  k_transpose<<<(G3C*CHc + 255)/256, 256, 0, stream>>>(cWhh, WhhTc, G3C, CHc);
  k_transpose<<<(G3H*KIN + 255)/256, 256, 0, stream>>>(gWih, WihTm, G3H, KIN);
  k_chargru<<<NTOK/8, 256, 0, stream>>>(chars, U2, WhhTc, cbhh, chh);
  k_gxmain<<<dim3(NTOK/64, G3H/64), 256, 0, stream>>>(x, wemb, chh, WihTm, gbih, gbhh, gxm);
  for(int t=0; t<TT; t++){
    const float* hin = (t & 1) ? hB : hA;
    float*       hout = (t & 1) ? hA : hB;
    k_grustep<<<HHm/4, 256, 0, stream>>>(hin, hout, gWhh, gxm, gbhh, ohT, t);
  }
  k_cls<<<TT, 256, 0, stream>>>(ohT, clsW, clsb, out);
}